// Round 1
// baseline (95421.484 us; speedup 1.0000x reference)
//
#include <hip/hip_runtime.h>
#include <hip/hip_bf16.h>
#include <math.h>

#define B_  256
#define T_  1024
#define DIN 256
#define H_  512
#define NG  2048   // 4H
#define L_  128
#define K1  768    // DIN + H
#define K2  1024   // 2H

typedef __hip_bfloat16 bf16;
typedef __bf16 bf16x8 __attribute__((ext_vector_type(8)));
typedef float  f32x4  __attribute__((ext_vector_type(4)));

// ---- ws layout (bytes) ----
#define OFF_W1P  0u              // bf16 [768][2048]
#define OFF_W2P  3145728u        // bf16 [1024][2048]
#define OFF_B1P  7340032u        // f32 [2048]
#define OFF_B2P  7348224u        // f32 [2048]
#define OFF_H1   7356416u        // bf16 [2][256][512]
#define OFF_H2   7880704u        // bf16 [2][256][512]
#define OFF_C1   8404992u        // f32 [256][512]
#define OFF_C2   8929280u        // f32 [256][512]
#define OFF_LOSS 9453568u        // f32 [1]

// ---------------- packing kernels ----------------
__global__ void pack_w1(const float* __restrict__ Wx1, const float* __restrict__ Wh1,
                        bf16* __restrict__ W1p) {
    int idx = blockIdx.x * 256 + threadIdx.x;      // 768*2048
    int k = idx >> 11;
    int n = idx & 2047;
    int col = ((n & 3) << 9) + (n >> 2);           // gate*512 + j
    float v = (k < DIN) ? Wx1[k * NG + col] : Wh1[(k - DIN) * NG + col];
    W1p[idx] = __float2bfloat16(v);
}

__global__ void pack_w2(const float* __restrict__ Wx2, const float* __restrict__ Wh2,
                        bf16* __restrict__ W2p) {
    int idx = blockIdx.x * 256 + threadIdx.x;      // 1024*2048
    int k = idx >> 11;
    int n = idx & 2047;
    int col = ((n & 3) << 9) + (n >> 2);
    float v = (k < H_) ? Wx2[k * NG + col] : Wh2[(k - H_) * NG + col];
    W2p[idx] = __float2bfloat16(v);
}

__global__ void pack_bias(const float* __restrict__ b1, const float* __restrict__ b2,
                          float* __restrict__ b1p, float* __restrict__ b2p) {
    int n = blockIdx.x * 256 + threadIdx.x;        // 2048
    int col = ((n & 3) << 9) + (n >> 2);
    b1p[n] = b1[col];
    b2p[n] = b2[col];
}

__global__ void zero_ws(float* __restrict__ p, int n) {
    int i = blockIdx.x * 256 + threadIdx.x;
    if (i < n) p[i] = 0.f;
}

// ---------------- LSTM step GEMM + gate epilogue ----------------
// Tile: M=32 (batch), N=64 (packed gate cols = 16 h-units), K-step 32.
// Grid: (2048/64=32, 256/32=8). 256 threads = 4 waves; wave w: rows w>>1, cols w&1.
#define TM 32
#define TN 64
#define TK 32

__launch_bounds__(256)
__global__ void lstm_step(const float* __restrict__ x, int t,
                          const bf16* __restrict__ a0, int len0,
                          const bf16* __restrict__ a1,
                          const bf16* __restrict__ Wp, const float* __restrict__ bp,
                          float* __restrict__ c, bf16* __restrict__ h_out, int K) {
    __shared__ bf16 Asub[TM][TK + 8];    // stride 40 bf16 (80B) -> 16B aligned rows
    __shared__ bf16 Bsub[TN][TK + 8];    // B staged transposed: [n][k]
    __shared__ float zbuf[TM][TN + 1];

    const int tid = threadIdx.x;
    const int n0 = blockIdx.x * TN;
    const int m0 = blockIdx.y * TM;

    const int lane = tid & 63;
    const int wid  = tid >> 6;
    const int wm   = wid >> 1;           // 0..1
    const int wn   = wid & 1;            // 0..1

    f32x4 acc0 = {0.f, 0.f, 0.f, 0.f};
    f32x4 acc1 = {0.f, 0.f, 0.f, 0.f};

    for (int k0 = 0; k0 < K; k0 += TK) {
        // stage A (32 rows x 32 k) as bf16
        #pragma unroll
        for (int i = 0; i < (TM * TK) / 256; ++i) {
            int idx = i * 256 + tid;
            int r = idx >> 5, kk = idx & 31;
            int k = k0 + kk;
            bf16 v;
            if (k < len0) {
                if (x) v = __float2bfloat16(x[(m0 + r) * (T_ * DIN) + t * DIN + k]);
                else   v = a0[(m0 + r) * len0 + k];
            } else {
                v = a1[(m0 + r) * H_ + (k - len0)];
            }
            Asub[r][kk] = v;
        }
        // stage B transposed: Bsub[n][k] = Wp[(k0+k)*2048 + n0+n]
        #pragma unroll
        for (int i = 0; i < (TK * TN) / 256; ++i) {
            int idx = i * 256 + tid;
            int k = idx >> 6, n = idx & 63;
            Bsub[n][k] = Wp[(k0 + k) * NG + n0 + n];
        }
        __syncthreads();

        const int kbase = (lane >> 4) * 8;
        bf16x8 af = *reinterpret_cast<const bf16x8*>(&Asub[wm * 16 + (lane & 15)][kbase]);
        bf16x8 bf0 = *reinterpret_cast<const bf16x8*>(&Bsub[wn * 32 + (lane & 15)][kbase]);
        bf16x8 bf1 = *reinterpret_cast<const bf16x8*>(&Bsub[wn * 32 + 16 + (lane & 15)][kbase]);
        acc0 = __builtin_amdgcn_mfma_f32_16x16x32_bf16(af, bf0, acc0, 0, 0, 0);
        acc1 = __builtin_amdgcn_mfma_f32_16x16x32_bf16(af, bf1, acc1, 0, 0, 0);
        __syncthreads();
    }

    // D layout (measured): col = lane&15, row = (lane>>4)*4 + v
    #pragma unroll
    for (int v = 0; v < 4; ++v) {
        int r = wm * 16 + (lane >> 4) * 4 + v;
        zbuf[r][wn * 32 + (lane & 15)]      = acc0[v];
        zbuf[r][wn * 32 + 16 + (lane & 15)] = acc1[v];
    }
    __syncthreads();

    // gate epilogue: 32 rows x 16 h-units
    #pragma unroll
    for (int i = 0; i < 2; ++i) {
        int p = i * 256 + tid;
        int r = p & 31, u = p >> 5;        // u in 0..15
        float zi = zbuf[r][u * 4 + 0] + bp[n0 + u * 4 + 0];
        float zf = zbuf[r][u * 4 + 1] + bp[n0 + u * 4 + 1];
        float zg = zbuf[r][u * 4 + 2] + bp[n0 + u * 4 + 2];
        float zo = zbuf[r][u * 4 + 3] + bp[n0 + u * 4 + 3];
        float ig = 1.f / (1.f + __expf(-zi));
        float fg = 1.f / (1.f + __expf(-zf));
        float gg = tanhf(zg);
        float og = 1.f / (1.f + __expf(-zo));
        int b = m0 + r;
        int j = (n0 >> 2) + u;
        float c_old = c[b * H_ + j];
        float c_new = fg * c_old + ig * gg;
        c[b * H_ + j] = c_new;
        h_out[b * H_ + j] = __float2bfloat16(og * tanhf(c_new));
    }
}

// ---------------- final projection + loss ----------------
__global__ void final_proj(const float* __restrict__ c2, const float* __restrict__ eps,
                           const float* __restrict__ w_mean, const float* __restrict__ b_mean,
                           const float* __restrict__ w_sigma, const float* __restrict__ b_sigma,
                           float* __restrict__ out, float* __restrict__ loss_acc) {
    __shared__ float feat[H_];
    __shared__ float red[L_];
    int b = blockIdx.x;
    int l = threadIdx.x;                 // 128 threads
    for (int k = l; k < H_; k += L_) feat[k] = c2[b * H_ + k];
    __syncthreads();
    float m = b_mean[l], s = b_sigma[l];
    for (int k = 0; k < H_; ++k) {
        float f = feat[k];
        m += f * w_mean[k * L_ + l];
        s += f * w_sigma[k * L_ + l];
    }
    float e = eps[b * L_ + l];
    out[b * L_ + l] = m + expf(0.5f * s) * e;
    float term = -0.5f * (1.f + s - m * m - expf(s));
    red[l] = term;
    __syncthreads();
    for (int off = 64; off > 0; off >>= 1) {
        if (l < off) red[l] += red[l + off];
        __syncthreads();
    }
    if (l == 0) atomicAdd(loss_acc, red[0]);
}

__global__ void write_loss(const float* __restrict__ loss_acc, float* __restrict__ out) {
    out[B_ * L_] = loss_acc[0] * (1.0f / (B_ * L_));
}

// ---------------- launch ----------------
extern "C" void kernel_launch(void* const* d_in, const int* in_sizes, int n_in,
                              void* d_out, int out_size, void* d_ws, size_t ws_size,
                              hipStream_t stream) {
    const float* x       = (const float*)d_in[0];
    const float* eps     = (const float*)d_in[1];
    const float* Wx1     = (const float*)d_in[2];
    const float* Wh1     = (const float*)d_in[3];
    const float* b1      = (const float*)d_in[4];
    const float* Wx2     = (const float*)d_in[5];
    const float* Wh2     = (const float*)d_in[6];
    const float* b2      = (const float*)d_in[7];
    const float* w_mean  = (const float*)d_in[8];
    const float* b_mean  = (const float*)d_in[9];
    const float* w_sigma = (const float*)d_in[10];
    const float* b_sigma = (const float*)d_in[11];

    char* ws = (char*)d_ws;
    bf16*  W1p  = (bf16*)(ws + OFF_W1P);
    bf16*  W2p  = (bf16*)(ws + OFF_W2P);
    float* b1p  = (float*)(ws + OFF_B1P);
    float* b2p  = (float*)(ws + OFF_B2P);
    bf16*  h1   = (bf16*)(ws + OFF_H1);
    bf16*  h2   = (bf16*)(ws + OFF_H2);
    float* c1   = (float*)(ws + OFF_C1);
    float* c2   = (float*)(ws + OFF_C2);
    float* loss = (float*)(ws + OFF_LOSS);

    pack_w1<<<6144, 256, 0, stream>>>(Wx1, Wh1, W1p);
    pack_w2<<<8192, 256, 0, stream>>>(Wx2, Wh2, W2p);
    pack_bias<<<8, 256, 0, stream>>>(b1, b2, b1p, b2p);
    // zero h1/h2/c1/c2/loss region (bf16 zero == 0x0000)
    zero_ws<<<2049, 256, 0, stream>>>((float*)(ws + OFF_H1), 524289);

    dim3 grid(NG / TN, B_ / TM);   // (32, 8)
    for (int t = 0; t < T_; ++t) {
        const bf16* h1r = h1 + (t & 1) * (B_ * H_);
        bf16*       h1w = h1 + ((t + 1) & 1) * (B_ * H_);
        const bf16* h2r = h2 + (t & 1) * (B_ * H_);
        bf16*       h2w = h2 + ((t + 1) & 1) * (B_ * H_);
        lstm_step<<<grid, 256, 0, stream>>>(x, t, nullptr, DIN, h1r, W1p, b1p, c1, h1w, K1);
        lstm_step<<<grid, 256, 0, stream>>>(nullptr, 0, h1w, H_, h2r, W2p, b2p, c2, h2w, K2);
    }

    final_proj<<<B_, L_, 0, stream>>>(c2, eps, w_mean, b_mean, w_sigma, b_sigma,
                                      (float*)d_out, loss);
    write_loss<<<1, 1, 0, stream>>>(loss, (float*)d_out);
}

// Round 2
// 25258.752 us; speedup vs baseline: 3.7778x; 3.7778x over previous
//
#include <hip/hip_runtime.h>
#include <hip/hip_bf16.h>
#include <math.h>

#define B_  256
#define T_  1024
#define DIN 256
#define H_  512
#define NG  2048   // 4H
#define L_  128

typedef __hip_bfloat16 bf16;
typedef __bf16 bf16x8 __attribute__((ext_vector_type(8)));
typedef float  f32x4  __attribute__((ext_vector_type(4)));

// ---- ws layout (bytes) ----
#define OFF_WF1  0u              // bf16 [32][24][4][64][8]  = 3,145,728 B
#define OFF_WF2  3145728u        // bf16 [32][32][4][64][8]  = 4,194,304 B
#define OFF_B1P  7340032u        // f32 [2048]
#define OFF_B2P  7348224u        // f32 [2048]
#define OFF_H1   7356416u        // bf16 [2][256][512] = 524,288 B
#define OFF_H2   7880704u        // bf16 [2][256][512]
#define OFF_C2   8404992u        // f32 [256][512]
#define OFF_SYNC 8929280u        // ctr[g] at +g*128; loss at +512

// ---------------- packing kernels ----------------
// Repack weights directly into per-block MFMA fragment order:
// frag[(nb*KS + ks)*4 + nt][lane][e]: packed col = nb*64 + nt*16 + (lane&15),
// k = ks*32 + (lane>>4)*8 + e.  Packed col n = unit*4 + gate (gate-interleaved).
__global__ void pack_wf(const float* __restrict__ Wx, const float* __restrict__ Wh,
                        int len0, int KS, bf16* __restrict__ out) {
    const int ks = blockIdx.x;
    const int nb = blockIdx.y;
    const int i  = threadIdx.x;            // 0..511
    const int nt   = i >> 7;
    const int lane = (i >> 1) & 63;
    const int ep   = (i & 1) * 4;
    const int colp = nb * 64 + nt * 16 + (lane & 15);
    const int orig_col = ((colp & 3) << 9) + (colp >> 2);
    const int kbase = ks * 32 + (lane >> 4) * 8 + ep;
    size_t obase = (((size_t)(nb * KS + ks) * 4 + nt) * 512) + lane * 8 + ep;
    #pragma unroll
    for (int e = 0; e < 4; ++e) {
        int k = kbase + e;
        float v = (k < len0) ? Wx[(size_t)k * NG + orig_col]
                             : Wh[(size_t)(k - len0) * NG + orig_col];
        out[obase + e] = __float2bfloat16(v);
    }
}

__global__ void pack_bias(const float* __restrict__ b1, const float* __restrict__ b2,
                          float* __restrict__ b1p, float* __restrict__ b2p) {
    int n = blockIdx.x * 256 + threadIdx.x;        // 2048
    int col = ((n & 3) << 9) + (n >> 2);
    b1p[n] = b1[col];
    b2p[n] = b2[col];
}

__global__ void zero_ws(float* __restrict__ p, int n) {
    int i = blockIdx.x * 256 + threadIdx.x;
    if (i < n) p[i] = 0.f;
}

// ---------------- helpers ----------------
__device__ __forceinline__ bf16x8 cvt8(const float* p) {
    union { bf16x8 v; __hip_bfloat16 h[8]; } u;
    const float4 a = *(const float4*)p;
    const float4 b = *(const float4*)(p + 4);
    u.h[0] = __float2bfloat16(a.x); u.h[1] = __float2bfloat16(a.y);
    u.h[2] = __float2bfloat16(a.z); u.h[3] = __float2bfloat16(a.w);
    u.h[4] = __float2bfloat16(b.x); u.h[5] = __float2bfloat16(b.y);
    u.h[6] = __float2bfloat16(b.z); u.h[7] = __float2bfloat16(b.w);
    return u.v;
}

__device__ __forceinline__ float sigm_f(float x) { return 1.f / (1.f + __expf(-x)); }
__device__ __forceinline__ float tanh_f(float x) {
    x = fminf(15.f, fmaxf(-15.f, x));
    float e = __expf(2.f * x);
    return (e - 1.f) / (e + 1.f);
}

// agent-scope write-through store (visible cross-XCD once vmcnt retires; no L2 wb fence needed)
__device__ __forceinline__ void store_h(bf16* p, float v) {
    union { __hip_bfloat16 h; unsigned short u; } c;
    c.h = __float2bfloat16(v);
    __hip_atomic_store((unsigned short*)p, c.u, __ATOMIC_RELAXED, __HIP_MEMORY_SCOPE_AGENT);
}

// gate epilogue: lane holds gates v=0..3 of cell (row, unit) in acc[bi][ni][v]
__device__ __forceinline__ void gate_epilogue(f32x4 (&acc)[2][2], float (&c)[2][2],
                                              const float4 (&bias)[2], bf16* hw,
                                              int rowbase, int unitbase) {
    #pragma unroll
    for (int bi = 0; bi < 2; ++bi) {
        #pragma unroll
        for (int ni = 0; ni < 2; ++ni) {
            const float4 bb = bias[ni];
            float zi = acc[bi][ni][0] + bb.x;
            float zf = acc[bi][ni][1] + bb.y;
            float zg = acc[bi][ni][2] + bb.z;
            float zo = acc[bi][ni][3] + bb.w;
            float ig = sigm_f(zi), fg = sigm_f(zf), gg = tanh_f(zg), og = sigm_f(zo);
            float cn = fg * c[bi][ni] + ig * gg;
            c[bi][ni] = cn;
            int row = rowbase + bi * 16;
            int unit = unitbase + ni * 4;
            store_h(hw + (size_t)row * H_ + unit, og * tanh_f(cn));
        }
    }
}

#define MFMA4(w0, w1, a0, a1)                                                        \
    acc[0][0] = __builtin_amdgcn_mfma_f32_16x16x32_bf16(w0, a0, acc[0][0], 0, 0, 0); \
    acc[0][1] = __builtin_amdgcn_mfma_f32_16x16x32_bf16(w1, a0, acc[0][1], 0, 0, 0); \
    acc[1][0] = __builtin_amdgcn_mfma_f32_16x16x32_bf16(w0, a1, acc[1][0], 0, 0, 0); \
    acc[1][1] = __builtin_amdgcn_mfma_f32_16x16x32_bf16(w1, a1, acc[1][1], 0, 0, 0);

// ---------------- persistent 2-layer LSTM ----------------
// 256 blocks x 256 thr; 128KB dyn LDS => 1 block/CU => all co-resident.
// group g = bid>>6 owns batches [g*64, g*64+64). r = bid&63: r<32 -> L1 role, else L2.
// Layer-pipelined: step s: L1 computes t=s, L2 computes t=s-1. 64-block barrier/step.
__launch_bounds__(256, 1)
__global__ void lstm_persist(const float* __restrict__ x,
                             const bf16* __restrict__ WF1, const bf16* __restrict__ WF2,
                             const float* __restrict__ b1p, const float* __restrict__ b2p,
                             bf16* __restrict__ h1, bf16* __restrict__ h2,
                             float* __restrict__ c2out, unsigned int* ctrs) {
    extern __shared__ char smem[];
    bf16* WL = (bf16*)smem;

    const int bid = blockIdx.x;
    const int g   = bid >> 6;
    const int r   = bid & 63;
    const bool isL1 = (r < 32);
    const int nb  = isL1 ? r : (r - 32);
    const int tid  = threadIdx.x;
    const int lane = tid & 63;
    const int wid  = tid >> 6;
    const int wm   = wid >> 1;   // batch half (0..1)
    const int wn   = wid & 1;    // n half (0..1)
    unsigned int* ctr = ctrs + g * 32;   // 128B apart

    // stage W fragments into LDS (once)
    {
        const float4* src = (const float4*)(isL1 ? (WF1 + (size_t)nb * (24 * 2048))
                                                 : (WF2 + (size_t)nb * (32 * 2048)));
        float4* dst = (float4*)WL;
        const int n16 = isL1 ? 6144 : 8192;
        for (int i = tid; i < n16; i += 256) dst[i] = src[i];
    }
    const float* bp = isL1 ? b1p : b2p;
    const int lh = lane >> 4;   // 0..3
    const int ll = lane & 15;
    float4 bias[2];
    bias[0] = *(const float4*)&bp[nb * 64 + (wn * 2 + 0) * 16 + lh * 4];
    bias[1] = *(const float4*)&bp[nb * 64 + (wn * 2 + 1) * 16 + lh * 4];
    float c[2][2] = {{0.f, 0.f}, {0.f, 0.f}};
    const int rowbase = g * 64 + wm * 32 + ll;
    const int unitbase = nb * 16 + wn * 8 + lh;
    const int koff = lh * 8;
    __syncthreads();

    for (int s = 0; s <= T_; ++s) {
        if (isL1) {
            if (s < T_) {
                const int t = s;
                const bf16* h1r = h1 + (size_t)((t + 1) & 1) * (B_ * H_);  // h1[t-1]
                bf16*       h1w = h1 + (size_t)(t & 1) * (B_ * H_);        // h1[t]
                f32x4 acc[2][2] = {};
                const float* x0 = x + (size_t)rowbase * (T_ * DIN) + (size_t)t * DIN + koff;
                const float* x1 = x0 + (size_t)16 * (T_ * DIN);
                #pragma unroll
                for (int ks = 0; ks < 8; ++ks) {
                    bf16x8 a0 = cvt8(x0 + ks * 32);
                    bf16x8 a1 = cvt8(x1 + ks * 32);
                    const bf16* wl = WL + (size_t)(ks * 4 + wn * 2) * 512 + lane * 8;
                    bf16x8 w0 = *(const bf16x8*)wl;
                    bf16x8 w1 = *(const bf16x8*)(wl + 512);
                    MFMA4(w0, w1, a0, a1)
                }
                const bf16* hp0 = h1r + (size_t)rowbase * H_ + koff;
                const bf16* hp1 = hp0 + 16 * H_;
                #pragma unroll
                for (int ks = 8; ks < 24; ++ks) {
                    bf16x8 a0 = *(const bf16x8*)(hp0 + (ks - 8) * 32);
                    bf16x8 a1 = *(const bf16x8*)(hp1 + (ks - 8) * 32);
                    const bf16* wl = WL + (size_t)(ks * 4 + wn * 2) * 512 + lane * 8;
                    bf16x8 w0 = *(const bf16x8*)wl;
                    bf16x8 w1 = *(const bf16x8*)(wl + 512);
                    MFMA4(w0, w1, a0, a1)
                }
                gate_epilogue(acc, c, bias, h1w, rowbase, unitbase);
            }
        } else {
            if (s >= 1) {
                const int t = s - 1;
                const bf16* h1c = h1 + (size_t)(t & 1) * (B_ * H_);        // h1[t]
                const bf16* h2r = h2 + (size_t)((t + 1) & 1) * (B_ * H_);  // h2[t-1]
                bf16*       h2w = h2 + (size_t)(t & 1) * (B_ * H_);        // h2[t]
                f32x4 acc[2][2] = {};
                const bf16* p0 = h1c + (size_t)rowbase * H_ + koff;
                const bf16* p1 = p0 + 16 * H_;
                #pragma unroll
                for (int ks = 0; ks < 16; ++ks) {
                    bf16x8 a0 = *(const bf16x8*)(p0 + ks * 32);
                    bf16x8 a1 = *(const bf16x8*)(p1 + ks * 32);
                    const bf16* wl = WL + (size_t)(ks * 4 + wn * 2) * 512 + lane * 8;
                    bf16x8 w0 = *(const bf16x8*)wl;
                    bf16x8 w1 = *(const bf16x8*)(wl + 512);
                    MFMA4(w0, w1, a0, a1)
                }
                const bf16* q0 = h2r + (size_t)rowbase * H_ + koff;
                const bf16* q1 = q0 + 16 * H_;
                #pragma unroll
                for (int ks = 16; ks < 32; ++ks) {
                    bf16x8 a0 = *(const bf16x8*)(q0 + (ks - 16) * 32);
                    bf16x8 a1 = *(const bf16x8*)(q1 + (ks - 16) * 32);
                    const bf16* wl = WL + (size_t)(ks * 4 + wn * 2) * 512 + lane * 8;
                    bf16x8 w0 = *(const bf16x8*)wl;
                    bf16x8 w1 = *(const bf16x8*)(wl + 512);
                    MFMA4(w0, w1, a0, a1)
                }
                gate_epilogue(acc, c, bias, h2w, rowbase, unitbase);
            }
        }
        if (s < T_) {
            // group barrier: stores already agent-visible (atomic write-through);
            // __syncthreads drains vmcnt for the whole block.
            __syncthreads();
            if (tid == 0) {
                __hip_atomic_fetch_add(ctr, 1u, __ATOMIC_RELEASE, __HIP_MEMORY_SCOPE_AGENT);
                const unsigned tgt = 64u * (unsigned)(s + 1);
                while (__hip_atomic_load(ctr, __ATOMIC_RELAXED, __HIP_MEMORY_SCOPE_AGENT) < tgt)
                    __builtin_amdgcn_s_sleep(2);
            }
            __syncthreads();
            __builtin_amdgcn_fence(__ATOMIC_ACQUIRE, "agent");  // invalidate stale L1/L2
        }
    }

    if (!isL1) {
        #pragma unroll
        for (int bi = 0; bi < 2; ++bi) {
            #pragma unroll
            for (int ni = 0; ni < 2; ++ni) {
                int row = rowbase + bi * 16;
                int unit = unitbase + ni * 4;
                c2out[(size_t)row * H_ + unit] = c[bi][ni];
            }
        }
    }
}

// ---------------- final projection + loss ----------------
__global__ void final_proj(const float* __restrict__ c2, const float* __restrict__ eps,
                           const float* __restrict__ w_mean, const float* __restrict__ b_mean,
                           const float* __restrict__ w_sigma, const float* __restrict__ b_sigma,
                           float* __restrict__ out, float* __restrict__ loss_acc) {
    __shared__ float feat[H_];
    __shared__ float red[L_];
    int b = blockIdx.x;
    int l = threadIdx.x;                 // 128 threads
    for (int k = l; k < H_; k += L_) feat[k] = c2[(size_t)b * H_ + k];
    __syncthreads();
    float m = b_mean[l], s = b_sigma[l];
    for (int k = 0; k < H_; ++k) {
        float f = feat[k];
        m += f * w_mean[k * L_ + l];
        s += f * w_sigma[k * L_ + l];
    }
    float e = eps[b * L_ + l];
    out[b * L_ + l] = m + expf(0.5f * s) * e;
    float term = -0.5f * (1.f + s - m * m - expf(s));
    red[l] = term;
    __syncthreads();
    for (int off = 64; off > 0; off >>= 1) {
        if (l < off) red[l] += red[l + off];
        __syncthreads();
    }
    if (l == 0) atomicAdd(loss_acc, red[0]);
}

__global__ void write_loss(const float* __restrict__ loss_acc, float* __restrict__ out) {
    out[B_ * L_] = loss_acc[0] * (1.0f / (B_ * L_));
}

// ---------------- launch ----------------
extern "C" void kernel_launch(void* const* d_in, const int* in_sizes, int n_in,
                              void* d_out, int out_size, void* d_ws, size_t ws_size,
                              hipStream_t stream) {
    const float* x       = (const float*)d_in[0];
    const float* eps     = (const float*)d_in[1];
    const float* Wx1     = (const float*)d_in[2];
    const float* Wh1     = (const float*)d_in[3];
    const float* b1      = (const float*)d_in[4];
    const float* Wx2     = (const float*)d_in[5];
    const float* Wh2     = (const float*)d_in[6];
    const float* b2      = (const float*)d_in[7];
    const float* w_mean  = (const float*)d_in[8];
    const float* b_mean  = (const float*)d_in[9];
    const float* w_sigma = (const float*)d_in[10];
    const float* b_sigma = (const float*)d_in[11];

    char* ws = (char*)d_ws;
    bf16*  WF1  = (bf16*)(ws + OFF_WF1);
    bf16*  WF2  = (bf16*)(ws + OFF_WF2);
    float* b1p  = (float*)(ws + OFF_B1P);
    float* b2p  = (float*)(ws + OFF_B2P);
    bf16*  h1   = (bf16*)(ws + OFF_H1);
    bf16*  h2   = (bf16*)(ws + OFF_H2);
    float* c2   = (float*)(ws + OFF_C2);
    unsigned int* ctrs = (unsigned int*)(ws + OFF_SYNC);
    float* loss = (float*)(ws + OFF_SYNC + 512);

    pack_wf<<<dim3(24, 32), 512, 0, stream>>>(Wx1, Wh1, DIN, 24, WF1);
    pack_wf<<<dim3(32, 32), 512, 0, stream>>>(Wx2, Wh2, H_, 32, WF2);
    pack_bias<<<8, 256, 0, stream>>>(b1, b2, b1p, b2p);
    // zero h1+h2 (both slots) and sync region (ctrs + loss)
    zero_ws<<<1024, 256, 0, stream>>>((float*)(ws + OFF_H1), 262144);
    zero_ws<<<1, 256, 0, stream>>>((float*)(ws + OFF_SYNC), 256);

    lstm_persist<<<256, 256, 131072, stream>>>(x, WF1, WF2, b1p, b2p, h1, h2, c2, ctrs);

    final_proj<<<B_, L_, 0, stream>>>(c2, eps, w_mean, b_mean, w_sigma, b_sigma,
                                      (float*)d_out, loss);
    write_loss<<<1, 1, 0, stream>>>(loss, (float*)d_out);
}

// Round 6
// 17668.355 us; speedup vs baseline: 5.4007x; 1.4296x over previous
//
#include <hip/hip_runtime.h>
#include <hip/hip_bf16.h>
#include <math.h>

#define B_  256
#define T_  1024
#define DIN 256
#define H_  512
#define NG  2048   // 4H
#define L_  128
#define TD  (T_*DIN)
#define SLOT (B_*H_)      // elems per h slot (131072)
#define GSTRIDE 32768     // 32 nb * 1024 elems per group within a slot

typedef __hip_bfloat16 bf16;
typedef __bf16 bf16x8 __attribute__((ext_vector_type(8)));
typedef float  f32x4  __attribute__((ext_vector_type(4)));

// ---- ws layout (bytes) ----
#define OFF_WF1  0u              // bf16 [32][24][4][64][8]  = 3,145,728 B
#define OFF_WF2  3145728u        // bf16 [32][32][4][64][8]  = 4,194,304 B
#define OFF_B1P  7340032u        // f32 [2048]
#define OFF_B2P  7348224u        // f32 [2048]
#define OFF_H1   7356416u        // bf16 [2 slots][4 g][32 nb][64 row][16 u]
#define OFF_H2   7880704u
#define OFF_C2   8404992u        // f32 [256][512]
#define OFF_SYNC 8929280u        // u32 flags[4][64] spread 64B (16KB); loss f32 at +16384

// ---------------- packing kernels ----------------
// frag[(nb*KS + ks)*4 + nt][lane][e]: packed col = nb*64 + nt*16 + (lane&15),
// k = ks*32 + (lane>>4)*8 + e.  Packed col n = unit*4 + gate.
__global__ void pack_wf(const float* __restrict__ Wx, const float* __restrict__ Wh,
                        int len0, int KS, bf16* __restrict__ out) {
    const int ks = blockIdx.x;
    const int nb = blockIdx.y;
    const int i  = threadIdx.x;            // 0..511
    const int nt   = i >> 7;
    const int lane = (i >> 1) & 63;
    const int ep   = (i & 1) * 4;
    const int colp = nb * 64 + nt * 16 + (lane & 15);
    const int orig_col = ((colp & 3) << 9) + (colp >> 2);
    const int kbase = ks * 32 + (lane >> 4) * 8 + ep;
    size_t obase = (((size_t)(nb * KS + ks) * 4 + nt) * 512) + lane * 8 + ep;
    #pragma unroll
    for (int e = 0; e < 4; ++e) {
        int k = kbase + e;
        float v = (k < len0) ? Wx[(size_t)k * NG + orig_col]
                             : Wh[(size_t)(k - len0) * NG + orig_col];
        out[obase + e] = __float2bfloat16(v);
    }
}

__global__ void pack_bias(const float* __restrict__ b1, const float* __restrict__ b2,
                          float* __restrict__ b1p, float* __restrict__ b2p) {
    int n = blockIdx.x * 256 + threadIdx.x;        // 2048
    int col = ((n & 3) << 9) + (n >> 2);
    b1p[n] = b1[col];
    b2p[n] = b2[col];
}

__global__ void zero_ws(float* __restrict__ p, int n) {
    int i = blockIdx.x * 256 + threadIdx.x;
    if (i < n) p[i] = 0.f;
}

// ---------------- helpers ----------------
__device__ __forceinline__ bf16x8 cvt8(const float* p) {
    union { bf16x8 v; __hip_bfloat16 h[8]; } u;
    const float4 a = *(const float4*)p;
    const float4 b = *(const float4*)(p + 4);
    u.h[0] = __float2bfloat16(a.x); u.h[1] = __float2bfloat16(a.y);
    u.h[2] = __float2bfloat16(a.z); u.h[3] = __float2bfloat16(a.w);
    u.h[4] = __float2bfloat16(b.x); u.h[5] = __float2bfloat16(b.y);
    u.h[6] = __float2bfloat16(b.z); u.h[7] = __float2bfloat16(b.w);
    return u.v;
}

__device__ __forceinline__ float sigm_f(float x) { return 1.f / (1.f + __expf(-x)); }
__device__ __forceinline__ float tanh_f(float x) {
    x = fminf(15.f, fmaxf(-15.f, x));
    float e = __expf(2.f * x);
    return (e - 1.f) / (e + 1.f);
}

// 4 MFMA: one K-step (32) over all 4 n-tiles, W fragments from LDS
__device__ __forceinline__ void kstep(f32x4 (&acc)[4], const bf16* wl_, bf16x8 a) {
    acc[0] = __builtin_amdgcn_mfma_f32_16x16x32_bf16(*(const bf16x8*)(wl_),        a, acc[0], 0, 0, 0);
    acc[1] = __builtin_amdgcn_mfma_f32_16x16x32_bf16(*(const bf16x8*)(wl_ + 512),  a, acc[1], 0, 0, 0);
    acc[2] = __builtin_amdgcn_mfma_f32_16x16x32_bf16(*(const bf16x8*)(wl_ + 1024), a, acc[2], 0, 0, 0);
    acc[3] = __builtin_amdgcn_mfma_f32_16x16x32_bf16(*(const bf16x8*)(wl_ + 1536), a, acc[3], 0, 0, 0);
}

// x-part of layer-1 (K 0..255) into acc, independent of h -> used to hide barrier
__device__ __forceinline__ void xpart(const float* xp, const bf16* WL, int lane, f32x4 (&acc)[4]) {
    #pragma unroll
    for (int ks = 0; ks < 8; ++ks) {
        bf16x8 a = cvt8(xp + ks * 32);
        kstep(acc, WL + (size_t)(ks * 4) * 512 + lane * 8, a);
    }
}

__device__ __forceinline__ void epilogue(f32x4 (&acc)[4], float (&c)[4],
                                         const float4 (&bias)[4], bf16* hstage,
                                         int rowL, int lh) {
    #pragma unroll
    for (int nt = 0; nt < 4; ++nt) {
        float zi = acc[nt][0] + bias[nt].x;
        float zf = acc[nt][1] + bias[nt].y;
        float zg = acc[nt][2] + bias[nt].z;
        float zo = acc[nt][3] + bias[nt].w;
        float ig = sigm_f(zi), fg = sigm_f(zf), gg = tanh_f(zg), og = sigm_f(zo);
        float cn = fg * c[nt] + ig * gg;
        c[nt] = cn;
        hstage[rowL * 16 + nt * 4 + lh] = __float2bfloat16(og * tanh_f(cn));
    }
}

// ---------------- persistent 2-layer LSTM ----------------
// 256 blocks x 256 thr; >64KB dyn LDS => 1 block/CU => all co-resident (proven in R2).
// group g = bid>>6 owns batches [g*64, g*64+64). r = bid&63: r<32 -> L1, else L2.
// 4 waves/block: wave wid owns rows wid*16..+15, all 64 packed cols (no dup loads).
__launch_bounds__(256, 1)
__global__ void lstm_persist(const float* __restrict__ x,
                             const bf16* __restrict__ WF1, const bf16* __restrict__ WF2,
                             const float* __restrict__ b1p, const float* __restrict__ b2p,
                             bf16* __restrict__ h1, bf16* __restrict__ h2,
                             float* __restrict__ c2out, unsigned int* __restrict__ flags) {
    extern __shared__ char smem[];
    bf16* hstage = (bf16*)smem;              // 2KB staging tile [64][16]
    bf16* WL = (bf16*)(smem + 2048);         // up to 128KB W fragments

    const int bid = blockIdx.x;
    const int g   = bid >> 6;
    const int r   = bid & 63;
    const bool isL1 = (r < 32);
    const int nb  = isL1 ? r : (r - 32);
    const int tid  = threadIdx.x;
    const int lane = tid & 63;
    const int wid  = tid >> 6;
    const int lh = lane >> 4, ll = lane & 15;
    const int rowL = wid * 16 + ll;          // 0..63
    const int row  = g * 64 + rowL;

    // stage W fragments into LDS (once)
    {
        const float4* src = (const float4*)(isL1 ? (WF1 + (size_t)nb * (24 * 2048))
                                                 : (WF2 + (size_t)nb * (32 * 2048)));
        float4* dst = (float4*)WL;
        const int n16 = isL1 ? 6144 : 8192;
        for (int i = tid; i < n16; i += 256) dst[i] = src[i];
    }
    const float* bp = isL1 ? b1p : b2p;
    float4 bias[4];
    #pragma unroll
    for (int nt = 0; nt < 4; ++nt)
        bias[nt] = *(const float4*)&bp[nb * 64 + nt * 16 + lh * 4];
    float c[4] = {0.f, 0.f, 0.f, 0.f};
    unsigned int* myflag   = flags + (g * 64 + r) * 16;    // 64B apart
    unsigned int* pollflag = flags + (g * 64 + lane) * 16;
    // per-lane offset into an h tile buffer (consumer side)
    const int hoff = ((lh >> 1) << 10) + rowL * 16 + (lh & 1) * 8;
    const float* xrow = x + (size_t)row * TD + lh * 8;

    __syncthreads();   // weights ready

    f32x4 accx[4] = {};
    if (isL1) xpart(xrow, WL, lane, accx);   // t=0 x-part

    for (int s = 0; s <= T_; ++s) {
        unsigned int* out32 = nullptr;
        if (isL1) {
            if (s < T_) {
                const int t = s;
                f32x4 acc[4] = {accx[0], accx[1], accx[2], accx[3]};
                if (t > 0) {
                    const bf16* hb = h1 + (size_t)((t + 1) & 1) * SLOT + g * GSTRIDE + hoff;
                    #pragma unroll
                    for (int ksh = 0; ksh < 16; ++ksh) {
                        bf16x8 a = *(const bf16x8*)(hb + ksh * 2048);
                        kstep(acc, WL + (size_t)((8 + ksh) * 4) * 512 + lane * 8, a);
                    }
                }
                epilogue(acc, c, bias, hstage, rowL, lh);
                out32 = (unsigned int*)(h1 + (size_t)(t & 1) * SLOT + (size_t)(g * 32 + nb) * 1024);
            }
        } else {
            if (s >= 1) {
                const int t = s - 1;
                f32x4 acc[4] = {};
                const bf16* hb1 = h1 + (size_t)(t & 1) * SLOT + g * GSTRIDE + hoff;
                #pragma unroll
                for (int ksh = 0; ksh < 16; ++ksh) {
                    bf16x8 a = *(const bf16x8*)(hb1 + ksh * 2048);
                    kstep(acc, WL + (size_t)(ksh * 4) * 512 + lane * 8, a);
                }
                if (t > 0) {
                    const bf16* hb2 = h2 + (size_t)((t + 1) & 1) * SLOT + g * GSTRIDE + hoff;
                    #pragma unroll
                    for (int ksh = 0; ksh < 16; ++ksh) {
                        bf16x8 a = *(const bf16x8*)(hb2 + ksh * 2048);
                        kstep(acc, WL + (size_t)((16 + ksh) * 4) * 512 + lane * 8, a);
                    }
                }
                epilogue(acc, c, bias, hstage, rowL, lh);
                out32 = (unsigned int*)(h2 + (size_t)(t & 1) * SLOT + (size_t)(g * 32 + nb) * 1024);
            }
        }
        if (s < T_) {
            __syncthreads();                 // hstage tile complete
            if (out32) {
                const unsigned int* hs = (const unsigned int*)hstage;
                __hip_atomic_store(out32 + tid,       hs[tid],
                                   __ATOMIC_RELAXED, __HIP_MEMORY_SCOPE_AGENT);
                __hip_atomic_store(out32 + tid + 256, hs[tid + 256],
                                   __ATOMIC_RELAXED, __HIP_MEMORY_SCOPE_AGENT);
            }
            __syncthreads();                 // vmcnt(0) drain before barrier => stores done
            if (tid == 0)
                __hip_atomic_fetch_add(myflag, 1u, __ATOMIC_ACQ_REL, __HIP_MEMORY_SCOPE_AGENT);
            // hide barrier latency: precompute next step's x-part (h-independent)
            if (isL1 && s + 1 < T_) {
                #pragma unroll
                for (int nt = 0; nt < 4; ++nt) accx[nt] = (f32x4){0.f, 0.f, 0.f, 0.f};
                xpart(xrow + (size_t)(s + 1) * DIN, WL, lane, accx);
            }
            if (wid == 0) {
                const unsigned tgt = (unsigned)(s + 1);
                unsigned v = __hip_atomic_load(pollflag, __ATOMIC_RELAXED, __HIP_MEMORY_SCOPE_AGENT);
                while (v < tgt) {
                    __builtin_amdgcn_s_sleep(2);
                    v = __hip_atomic_load(pollflag, __ATOMIC_RELAXED, __HIP_MEMORY_SCOPE_AGENT);
                }
            }
            __syncthreads();
            __builtin_amdgcn_fence(__ATOMIC_ACQUIRE, "agent");  // invalidate stale L0/L2
        }
    }

    if (!isL1) {
        #pragma unroll
        for (int nt = 0; nt < 4; ++nt)
            c2out[(size_t)row * H_ + nb * 16 + nt * 4 + lh] = c[nt];
    }
}

// ---------------- final projection + loss ----------------
__global__ void final_proj(const float* __restrict__ c2, const float* __restrict__ eps,
                           const float* __restrict__ w_mean, const float* __restrict__ b_mean,
                           const float* __restrict__ w_sigma, const float* __restrict__ b_sigma,
                           float* __restrict__ out, float* __restrict__ loss_acc) {
    __shared__ float feat[H_];
    __shared__ float red[L_];
    int b = blockIdx.x;
    int l = threadIdx.x;                 // 128 threads
    for (int k = l; k < H_; k += L_) feat[k] = c2[(size_t)b * H_ + k];
    __syncthreads();
    float m = b_mean[l], s = b_sigma[l];
    for (int k = 0; k < H_; ++k) {
        float f = feat[k];
        m += f * w_mean[k * L_ + l];
        s += f * w_sigma[k * L_ + l];
    }
    float e = eps[b * L_ + l];
    out[b * L_ + l] = m + expf(0.5f * s) * e;
    float term = -0.5f * (1.f + s - m * m - expf(s));
    red[l] = term;
    __syncthreads();
    for (int off = 64; off > 0; off >>= 1) {
        if (l < off) red[l] += red[l + off];
        __syncthreads();
    }
    if (l == 0) atomicAdd(loss_acc, red[0]);
}

__global__ void write_loss(const float* __restrict__ loss_acc, float* __restrict__ out) {
    out[B_ * L_] = loss_acc[0] * (1.0f / (B_ * L_));
}

// ---------------- launch ----------------
extern "C" void kernel_launch(void* const* d_in, const int* in_sizes, int n_in,
                              void* d_out, int out_size, void* d_ws, size_t ws_size,
                              hipStream_t stream) {
    const float* x       = (const float*)d_in[0];
    const float* eps     = (const float*)d_in[1];
    const float* Wx1     = (const float*)d_in[2];
    const float* Wh1     = (const float*)d_in[3];
    const float* b1      = (const float*)d_in[4];
    const float* Wx2     = (const float*)d_in[5];
    const float* Wh2     = (const float*)d_in[6];
    const float* b2      = (const float*)d_in[7];
    const float* w_mean  = (const float*)d_in[8];
    const float* b_mean  = (const float*)d_in[9];
    const float* w_sigma = (const float*)d_in[10];
    const float* b_sigma = (const float*)d_in[11];

    char* ws = (char*)d_ws;
    bf16*  WF1  = (bf16*)(ws + OFF_WF1);
    bf16*  WF2  = (bf16*)(ws + OFF_WF2);
    float* b1p  = (float*)(ws + OFF_B1P);
    float* b2p  = (float*)(ws + OFF_B2P);
    bf16*  h1   = (bf16*)(ws + OFF_H1);
    bf16*  h2   = (bf16*)(ws + OFF_H2);
    float* c2   = (float*)(ws + OFF_C2);
    unsigned int* flags = (unsigned int*)(ws + OFF_SYNC);
    float* loss = (float*)(ws + OFF_SYNC + 16384);

    pack_wf<<<dim3(24, 32), 512, 0, stream>>>(Wx1, Wh1, DIN, 24, WF1);
    pack_wf<<<dim3(32, 32), 512, 0, stream>>>(Wx2, Wh2, H_, 32, WF2);
    pack_bias<<<8, 256, 0, stream>>>(b1, b2, b1p, b2p);
    zero_ws<<<17, 256, 0, stream>>>((float*)(ws + OFF_SYNC), 4097);   // flags + loss

    lstm_persist<<<256, 256, 133120, stream>>>(x, WF1, WF2, b1p, b2p, h1, h2, c2, flags);

    final_proj<<<B_, L_, 0, stream>>>(c2, eps, w_mean, b_mean, w_sigma, b_sigma,
                                      (float*)d_out, loss);
    write_loss<<<1, 1, 0, stream>>>(loss, (float*)d_out);
}